// Round 1
// baseline (3147.596 us; speedup 1.0000x reference)
//
#include <hip/hip_runtime.h>

typedef float f32x4 __attribute__((ext_vector_type(4)));
typedef short s16x8 __attribute__((ext_vector_type(8)));
typedef unsigned short u16;

#define B_    256
#define HW_   196
#define E_    1024
#define H_    1024
#define L_    128
#define T_    48
#define FCOUT 1154   // L + H + 2
#define FCPAD 1216   // next multiple of 64

__device__ __forceinline__ u16 f2bf(float x) {
  union { float f; unsigned u; } v; v.f = x;
  unsigned r = v.u + 0x7FFF + ((v.u >> 16) & 1);  // RNE
  return (u16)(r >> 16);
}
__device__ __forceinline__ float sigm(float x) { return 1.f / (1.f + expf(-x)); }

// ---------------------------------------------------------------------------
// Setup: strided fp32 -> bf16 convert (with zero row padding for W_fc)
// out[r*cols + c] = bf16(in[r*in_ld + in_off + c]) for r < src_rows else 0
// ---------------------------------------------------------------------------
__global__ __launch_bounds__(256) void cvt_bf16(
    const float* __restrict__ in, u16* __restrict__ out,
    int src_rows, int in_ld, int in_off, int cols, long total) {
  long idx = (long)blockIdx.x * 256 + threadIdx.x;
  if (idx >= total) return;
  int r = (int)(idx / cols);
  int c = (int)(idx % cols);
  float v = (r < src_rows) ? in[(size_t)r * in_ld + in_off + c] : 0.f;
  out[idx] = f2bf(v);
}

// ---------------------------------------------------------------------------
// img_mean[b][e] = mean over HW of image[b][hw][e]; store bf16
// ---------------------------------------------------------------------------
__global__ __launch_bounds__(256) void img_mean_k(
    const float* __restrict__ image, u16* __restrict__ meanB) {
  int idx = blockIdx.x * 256 + threadIdx.x;   // b*1024 + e
  int b = idx >> 10;
  const float* p = image + (size_t)b * HW_ * E_ + (idx & 1023);
  float s = 0.f;
  #pragma unroll 4
  for (int hw = 0; hw < HW_; ++hw) s += p[(size_t)hw * E_];
  meanB[idx] = f2bf(s * (1.0f / HW_));
}

// ---------------------------------------------------------------------------
// Elementwise LSTM cell update.
// gates layout (B x 4H): [i | f | g | o]
// ---------------------------------------------------------------------------
__global__ __launch_bounds__(256) void lstm_update(
    const float* __restrict__ gates, float* __restrict__ mstate,
    u16* __restrict__ h_bf) {
  int idx = blockIdx.x * 256 + threadIdx.x;   // b*1024 + j
  int b = idx >> 10, j = idx & 1023;
  const float* g = gates + (size_t)b * (4 * H_);
  float gi = g[j], gf = g[j + H_], gg = g[j + 2 * H_], go = g[j + 3 * H_];
  float m = mstate[idx];
  m = sigm(gf) * m + sigm(gi) * tanhf(gg);
  float h = sigm(go) * tanhf(m);
  mstate[idx] = m;
  h_bf[idx] = f2bf(h);
}

// ---------------------------------------------------------------------------
// Generic bf16 NT GEMM: C[M x N] = sum_k A[m][k] * B[n][k]
// Two K-segments (A0/B0 over K0, then A1/B1 over K1) so the per-step gates
// GEMM can consume [label_t | h] x [W_ihL | W_hh]^T without materializing the
// concatenation. BM=BN=BK=64, 256 threads = 4 waves, each wave 32x32 via
// 2x2 mfma_f32_16x16x32_bf16. LDS leading dim padded 64->72 (2-way bank
// aliasing only, which is free).
//
// MODE 0: outF = acc + bias1[n] + bias2[n]                  (gates_base)
// MODE 1: outB = bf16(tanh(acc + bias1[n]))                 (h0)
// MODE 2: outF = tanh(acc + bias1[n])                       (m0)
// MODE 3: outF = acc + Cin[m][n]                            (step gates)
// MODE 4: fc epilogue: relu(acc+b_fc[n]) -> masked scatter  (outputs)
// ---------------------------------------------------------------------------
template <int MODE>
__global__ __launch_bounds__(256) void gemm_nt(
    const u16* __restrict__ A0, int lda0, const u16* __restrict__ B0, int ldb0, int K0,
    const u16* __restrict__ A1, int lda1, const u16* __restrict__ B1, int ldb1, int K1,
    const float* __restrict__ bias1, const float* __restrict__ bias2,
    const float* __restrict__ Cin, float* __restrict__ outF, u16* __restrict__ outB,
    int ldc, const int* __restrict__ length, int t, float* __restrict__ dout) {
  __shared__ __align__(16) u16 As[64][72];
  __shared__ __align__(16) u16 Bs[64][72];

  const int m0 = blockIdx.x * 64;
  const int n0 = blockIdx.y * 64;
  const int tid  = threadIdx.x;
  const int lane = tid & 63;
  const int wave = tid >> 6;
  const int wm = wave & 1, wn = wave >> 1;     // 2x2 waves over the 64x64 tile
  const int quad = lane >> 4, l16 = lane & 15;

  const int loadRow = tid >> 3;        // 0..31
  const int loadCol = (tid & 7) * 8;   // 0,8,...,56

  f32x4 acc[2][2] = {};

  #pragma unroll
  for (int seg = 0; seg < 2; ++seg) {
    const u16* A  = seg ? A1 : A0;  const int lda = seg ? lda1 : lda0;
    const u16* Bp = seg ? B1 : B0;  const int ldb = seg ? ldb1 : ldb0;
    const int K   = seg ? K1 : K0;
    for (int kb = 0; kb < K; kb += 64) {
      __syncthreads();  // protect LDS from readers of previous tile
      #pragma unroll
      for (int p = 0; p < 2; ++p) {
        int r = loadRow + p * 32;
        *(uint4*)&As[r][loadCol] = *(const uint4*)&A [(size_t)(m0 + r) * lda + kb + loadCol];
        *(uint4*)&Bs[r][loadCol] = *(const uint4*)&Bp[(size_t)(n0 + r) * ldb + kb + loadCol];
      }
      __syncthreads();
      #pragma unroll
      for (int ks = 0; ks < 64; ks += 32) {
        s16x8 a0v = *(const s16x8*)&As[wm * 32      + l16][ks + quad * 8];
        s16x8 a1v = *(const s16x8*)&As[wm * 32 + 16 + l16][ks + quad * 8];
        s16x8 b0v = *(const s16x8*)&Bs[wn * 32      + l16][ks + quad * 8];
        s16x8 b1v = *(const s16x8*)&Bs[wn * 32 + 16 + l16][ks + quad * 8];
        acc[0][0] = __builtin_amdgcn_mfma_f32_16x16x32_bf16(a0v, b0v, acc[0][0], 0, 0, 0);
        acc[0][1] = __builtin_amdgcn_mfma_f32_16x16x32_bf16(a0v, b1v, acc[0][1], 0, 0, 0);
        acc[1][0] = __builtin_amdgcn_mfma_f32_16x16x32_bf16(a1v, b0v, acc[1][0], 0, 0, 0);
        acc[1][1] = __builtin_amdgcn_mfma_f32_16x16x32_bf16(a1v, b1v, acc[1][1], 0, 0, 0);
      }
    }
  }

  // Epilogue. C/D layout (verified m89/m91): row m = quad*4+reg, col n = lane&15.
  #pragma unroll
  for (int mi = 0; mi < 2; ++mi) {
    #pragma unroll
    for (int ni = 0; ni < 2; ++ni) {
      #pragma unroll
      for (int r = 0; r < 4; ++r) {
        int m = m0 + wm * 32 + mi * 16 + quad * 4 + r;
        int n = n0 + wn * 32 + ni * 16 + l16;
        float v = acc[mi][ni][r];
        if constexpr (MODE == 0) {
          outF[(size_t)m * ldc + n] = v + bias1[n] + bias2[n];
        } else if constexpr (MODE == 1) {
          outB[(size_t)m * ldc + n] = f2bf(tanhf(v + bias1[n]));
        } else if constexpr (MODE == 2) {
          outF[(size_t)m * ldc + n] = tanhf(v + bias1[n]);
        } else if constexpr (MODE == 3) {
          outF[(size_t)m * ldc + n] = v + Cin[(size_t)m * ldc + n];
        } else {  // MODE 4: fc outputs
          if (n < FCOUT) {
            float rv = fmaxf(v + bias1[n], 0.f);
            float msk = (t < length[m]) ? 1.f : 0.f;
            if (n < L_) {
              dout[(size_t)m * (T_ * L_) + t * L_ + n] = rv * msk;
            } else if (n < L_ + H_) {
              dout[(size_t)(B_ * T_ * L_) + (size_t)m * (T_ * H_) + t * H_ + (n - L_)] = rv * msk;
            } else if (n == L_ + H_) {
              dout[(size_t)B_ * T_ * (L_ + H_) + m * T_ + t] = expf(rv) * msk;
            } else {
              dout[(size_t)B_ * T_ * (L_ + H_ + 1) + m * T_ + t] = sigm(rv) * msk;
            }
          }
        }
      }
    }
  }
}

// ---------------------------------------------------------------------------
extern "C" void kernel_launch(void* const* d_in, const int* in_sizes, int n_in,
                              void* d_out, int out_size, void* d_ws, size_t ws_size,
                              hipStream_t stream) {
  const float* image  = (const float*)d_in[0];
  const float* label  = (const float*)d_in[1];
  const int*   length = (const int*)  d_in[2];
  const float* W_h    = (const float*)d_in[3];
  const float* b_h    = (const float*)d_in[4];
  const float* W_m    = (const float*)d_in[5];
  const float* b_m    = (const float*)d_in[6];
  const float* W_ih   = (const float*)d_in[7];
  const float* W_hh   = (const float*)d_in[8];
  const float* b_ih   = (const float*)d_in[9];
  const float* b_hh   = (const float*)d_in[10];
  const float* W_fc   = (const float*)d_in[11];
  const float* b_fc   = (const float*)d_in[12];
  float* out = (float*)d_out;

  char* ws = (char*)d_ws;
  size_t off = 0;
  auto alloc = [&](size_t bytes) -> void* {
    void* p = ws + off;
    off = (off + bytes + 255) & ~(size_t)255;
    return p;
  };
  u16*   meanB = (u16*)  alloc((size_t)B_ * E_ * 2);
  u16*   WhB   = (u16*)  alloc((size_t)H_ * E_ * 2);
  u16*   WmB   = (u16*)  alloc((size_t)H_ * E_ * 2);
  u16*   WihE  = (u16*)  alloc((size_t)4 * H_ * E_ * 2);
  u16*   WihL  = (u16*)  alloc((size_t)4 * H_ * L_ * 2);
  u16*   WhhB  = (u16*)  alloc((size_t)4 * H_ * H_ * 2);
  u16*   WfcB  = (u16*)  alloc((size_t)FCPAD * H_ * 2);
  u16*   labB  = (u16*)  alloc((size_t)B_ * T_ * L_ * 2);
  float* gbase = (float*)alloc((size_t)B_ * 4 * H_ * 4);
  float* gates = (float*)alloc((size_t)B_ * 4 * H_ * 4);
  u16*   hB    = (u16*)  alloc((size_t)B_ * H_ * 2);
  float* mS    = (float*)alloc((size_t)B_ * H_ * 4);

  auto cvt = [&](const float* in, u16* o, int rows, int src_rows, int in_ld,
                 int in_off, int cols) {
    long total = (long)rows * cols;
    int blocks = (int)((total + 255) / 256);
    cvt_bf16<<<blocks, 256, 0, stream>>>(in, o, src_rows, in_ld, in_off, cols, total);
  };

  // --- setup: weight/label conversion to bf16 ---
  cvt(W_h,  WhB,  H_,     H_,     E_,      0,  E_);
  cvt(W_m,  WmB,  H_,     H_,     E_,      0,  E_);
  cvt(W_ih, WihE, 4 * H_, 4 * H_, E_ + L_, 0,  E_);   // columns [0, E)
  cvt(W_ih, WihL, 4 * H_, 4 * H_, E_ + L_, E_, L_);   // columns [E, E+L)
  cvt(W_hh, WhhB, 4 * H_, 4 * H_, H_,      0,  H_);
  cvt(W_fc, WfcB, FCPAD,  FCOUT,  H_,      0,  H_);   // zero-padded rows
  cvt(label, labB, B_, B_, T_ * L_, 0, T_ * L_);

  img_mean_k<<<(B_ * E_) / 256, 256, 0, stream>>>(image, meanB);

  // --- setup GEMMs ---
  // h0 = tanh(mean @ W_h^T + b_h) -> bf16
  gemm_nt<1><<<dim3(B_ / 64, H_ / 64), 256, 0, stream>>>(
      meanB, E_, WhB, E_, E_,  meanB, E_, WhB, E_, 0,
      b_h, nullptr, nullptr, nullptr, hB, H_, nullptr, 0, nullptr);
  // m0 = tanh(mean @ W_m^T + b_m) -> f32
  gemm_nt<2><<<dim3(B_ / 64, H_ / 64), 256, 0, stream>>>(
      meanB, E_, WmB, E_, E_,  meanB, E_, WmB, E_, 0,
      b_m, nullptr, nullptr, mS, nullptr, H_, nullptr, 0, nullptr);
  // gates_base = mean @ W_ihE^T + b_ih + b_hh -> f32
  gemm_nt<0><<<dim3(B_ / 64, (4 * H_) / 64), 256, 0, stream>>>(
      meanB, E_, WihE, E_, E_,  meanB, E_, WihE, E_, 0,
      b_ih, b_hh, nullptr, gbase, nullptr, 4 * H_, nullptr, 0, nullptr);

  // --- the scan ---
  for (int t = 0; t < T_; ++t) {
    // gates = gates_base + lab_t @ W_ihL^T + h @ W_hh^T
    gemm_nt<3><<<dim3(B_ / 64, (4 * H_) / 64), 256, 0, stream>>>(
        labB + (size_t)t * L_, T_ * L_, WihL, L_, L_,
        hB, H_, WhhB, H_, H_,
        nullptr, nullptr, gbase, gates, nullptr, 4 * H_, nullptr, 0, nullptr);
    // m,h update
    lstm_update<<<(B_ * H_) / 256, 256, 0, stream>>>(gates, mS, hB);
    // out = relu(h @ W_fc^T + b_fc) -> masked scatter into 4 outputs
    gemm_nt<4><<<dim3(B_ / 64, FCPAD / 64), 256, 0, stream>>>(
        hB, H_, WfcB, H_, H_,  hB, H_, WfcB, H_, 0,
        b_fc, nullptr, nullptr, nullptr, nullptr, 0, length, t, out);
  }
}

// Round 3
// 1959.843 us; speedup vs baseline: 1.6060x; 1.6060x over previous
//
#include <hip/hip_runtime.h>

typedef float f32x4 __attribute__((ext_vector_type(4)));
typedef short s16x8 __attribute__((ext_vector_type(8)));
typedef unsigned short u16;

#define B_    256
#define HW_   196
#define E_    1024
#define H_    1024
#define L_    128
#define T_    48
#define FCOUT 1154   // L + H + 2
#define FCPAD 1216   // next multiple of 64

#define GJOBS 128            // gates tiles: (B/32) x (H/64) = 8 x 16
#define FJOBS 76             // fc tiles:    (B/64) x (FCPAD/64) = 4 x 19

__device__ __forceinline__ u16 f2bf(float x) {
  union { float f; unsigned u; } v; v.f = x;
  unsigned r = v.u + 0x7FFF + ((v.u >> 16) & 1);  // RNE
  return (u16)(r >> 16);
}
__device__ __forceinline__ float sigm(float x) { return 1.f / (1.f + expf(-x)); }

// ---------------------------------------------------------------------------
// Setup: strided fp32 -> bf16 convert (with zero row padding for W_fc)
// ---------------------------------------------------------------------------
__global__ __launch_bounds__(256) void cvt_bf16(
    const float* __restrict__ in, u16* __restrict__ out,
    int src_rows, int in_ld, int in_off, int cols, long total) {
  long idx = (long)blockIdx.x * 256 + threadIdx.x;
  if (idx >= total) return;
  int r = (int)(idx / cols);
  int c = (int)(idx % cols);
  float v = (r < src_rows) ? in[(size_t)r * in_ld + in_off + c] : 0.f;
  out[idx] = f2bf(v);
}

// ---------------------------------------------------------------------------
// img_mean[b][e] = mean over HW of image[b][hw][e]; store bf16
// ---------------------------------------------------------------------------
__global__ __launch_bounds__(256) void img_mean_k(
    const float* __restrict__ image, u16* __restrict__ meanB) {
  int idx = blockIdx.x * 256 + threadIdx.x;   // b*1024 + e
  int b = idx >> 10;
  const float* p = image + (size_t)b * HW_ * E_ + (idx & 1023);
  float s = 0.f;
  #pragma unroll 4
  for (int hw = 0; hw < HW_; ++hw) s += p[(size_t)hw * E_];
  meanB[idx] = f2bf(s * (1.0f / HW_));
}

// ---------------------------------------------------------------------------
// Setup NT GEMM (64x64 tile, 4 waves of 32x32 via 2x2 16x16x32 mfma).
// MODE 0: outF = acc + bias1[n] + bias2[n]     (gates_base)
// MODE 1: outB = bf16(tanh(acc + bias1[n]))    (h0)
// MODE 2: outF = tanh(acc + bias1[n])          (m0)
// ---------------------------------------------------------------------------
template <int MODE>
__global__ __launch_bounds__(256) void gemm_nt(
    const u16* __restrict__ A, int lda, const u16* __restrict__ Bp, int ldb, int K,
    const float* __restrict__ bias1, const float* __restrict__ bias2,
    float* __restrict__ outF, u16* __restrict__ outB, int ldc) {
  __shared__ __align__(16) u16 As[64][72];
  __shared__ __align__(16) u16 Bs[64][72];

  const int m0 = blockIdx.x * 64;
  const int n0 = blockIdx.y * 64;
  const int tid  = threadIdx.x;
  const int lane = tid & 63;
  const int wave = tid >> 6;
  const int wm = wave & 1, wn = wave >> 1;
  const int quad = lane >> 4, l16 = lane & 15;
  const int loadRow = tid >> 3;
  const int loadCol = (tid & 7) * 8;

  f32x4 acc[2][2] = {};

  for (int kb = 0; kb < K; kb += 64) {
    __syncthreads();
    #pragma unroll
    for (int p = 0; p < 2; ++p) {
      int r = loadRow + p * 32;
      *(uint4*)&As[r][loadCol] = *(const uint4*)&A [(size_t)(m0 + r) * lda + kb + loadCol];
      *(uint4*)&Bs[r][loadCol] = *(const uint4*)&Bp[(size_t)(n0 + r) * ldb + kb + loadCol];
    }
    __syncthreads();
    #pragma unroll
    for (int ks = 0; ks < 64; ks += 32) {
      s16x8 a0v = *(const s16x8*)&As[wm * 32      + l16][ks + quad * 8];
      s16x8 a1v = *(const s16x8*)&As[wm * 32 + 16 + l16][ks + quad * 8];
      s16x8 b0v = *(const s16x8*)&Bs[wn * 32      + l16][ks + quad * 8];
      s16x8 b1v = *(const s16x8*)&Bs[wn * 32 + 16 + l16][ks + quad * 8];
      acc[0][0] = __builtin_amdgcn_mfma_f32_16x16x32_bf16(a0v, b0v, acc[0][0], 0, 0, 0);
      acc[0][1] = __builtin_amdgcn_mfma_f32_16x16x32_bf16(a0v, b1v, acc[0][1], 0, 0, 0);
      acc[1][0] = __builtin_amdgcn_mfma_f32_16x16x32_bf16(a1v, b0v, acc[1][0], 0, 0, 0);
      acc[1][1] = __builtin_amdgcn_mfma_f32_16x16x32_bf16(a1v, b1v, acc[1][1], 0, 0, 0);
    }
  }

  #pragma unroll
  for (int mi = 0; mi < 2; ++mi) {
    #pragma unroll
    for (int ni = 0; ni < 2; ++ni) {
      #pragma unroll
      for (int r = 0; r < 4; ++r) {
        int m = m0 + wm * 32 + mi * 16 + quad * 4 + r;
        int n = n0 + wn * 32 + ni * 16 + l16;
        float v = acc[mi][ni][r];
        if constexpr (MODE == 0) {
          outF[(size_t)m * ldc + n] = v + bias1[n] + bias2[n];
        } else if constexpr (MODE == 1) {
          outB[(size_t)m * ldc + n] = f2bf(tanhf(v + bias1[n]));
        } else {
          outF[(size_t)m * ldc + n] = tanhf(v + bias1[n]);
        }
      }
    }
  }
}

// ---------------------------------------------------------------------------
// One scan phase per launch; kernel boundary = barrier + coherence (no
// reliance on grid.sync cross-XCD visibility — R2 failed there).
// Phase p (host loop, p = 0..T):
//   blocks [0,128):    gates(p) if p<T  : read hcur -> write hnext, mS
//   blocks [128,204):  fc(p-1)  if p>=1 : read hcur -> masked scatter to out
// Both consumers only read h(p-1) = hcur, written by the previous dispatch.
//
// Gates tile: 32 (b) x 64 (j), all 4 gates; wave g computes gate g's 32x64
// (2x4 frags of 16x16), then the LSTM update runs in-block via an LDS
// exchange. fc tile: 64x64, fc epilogue fused.
// ---------------------------------------------------------------------------
struct GShape { u16 A[32][72]; u16 B[256][72]; };   // 41472 B
struct FShape { u16 A[64][72]; u16 B[64][72]; };    // 18432 B
union SharedU {
  GShape g;
  FShape f;
  float gs[4][32][64];                              // 32768 B
};

__global__ __launch_bounds__(256) void step_k(
    const u16* __restrict__ labB,    // B x T x L
    const u16* __restrict__ WihL,    // 4H x L
    const u16* __restrict__ WhhB,    // 4H x H
    const u16* __restrict__ WfcB,    // FCPAD x H
    const float* __restrict__ gbase, // B x 4H (includes b_ih + b_hh)
    const float* __restrict__ b_fc,  // FCOUT
    const u16* __restrict__ hcur, u16* __restrict__ hnext,
    float* __restrict__ mS,          // B x H f32
    const int* __restrict__ length,
    float* __restrict__ out,
    int p) {
  __shared__ SharedU sh;

  const int bid  = blockIdx.x;
  const int tid  = threadIdx.x;
  const int lane = tid & 63;
  const int wave = tid >> 6;
  const int quad = lane >> 4, l16 = lane & 15;
  const int ar = tid >> 3;            // load row 0..31
  const int ac = (tid & 7) * 8;       // load col chunk

  if (p < T_ && bid < GJOBS) {
    // ---------------- gates(p) + LSTM update ----------------
    const int mb = bid >> 4;        // 0..7   (b tile of 32)
    const int jb = bid & 15;        // 0..15  (j tile of 64)
    f32x4 acc[2][4] = {};

    #pragma unroll
    for (int seg = 0; seg < 2; ++seg) {
      const u16* Asrc = seg ? hcur : (labB + (size_t)p * L_);
      const int  lda  = seg ? H_ : (T_ * L_);
      const u16* Bsrc = seg ? WhhB : WihL;
      const int  ldb  = seg ? H_ : L_;
      const int  K    = seg ? H_ : L_;
      for (int kb = 0; kb < K; kb += 64) {
        __syncthreads();
        *(uint4*)&sh.g.A[ar][ac] =
            *(const uint4*)&Asrc[(size_t)(mb * 32 + ar) * lda + kb + ac];
        #pragma unroll
        for (int q = 0; q < 8; ++q) {
          int rr = ar + q * 32;                       // 0..255
          int grow = (rr >> 6) * H_ + jb * 64 + (rr & 63);
          *(uint4*)&sh.g.B[rr][ac] =
              *(const uint4*)&Bsrc[(size_t)grow * ldb + kb + ac];
        }
        __syncthreads();
        #pragma unroll
        for (int ks = 0; ks < 64; ks += 32) {
          s16x8 av[2], bv[4];
          av[0] = *(const s16x8*)&sh.g.A[l16][ks + quad * 8];
          av[1] = *(const s16x8*)&sh.g.A[16 + l16][ks + quad * 8];
          #pragma unroll
          for (int ni = 0; ni < 4; ++ni)
            bv[ni] = *(const s16x8*)&sh.g.B[wave * 64 + ni * 16 + l16][ks + quad * 8];
          #pragma unroll
          for (int mi = 0; mi < 2; ++mi)
            #pragma unroll
            for (int ni = 0; ni < 4; ++ni)
              acc[mi][ni] = __builtin_amdgcn_mfma_f32_16x16x32_bf16(
                  av[mi], bv[ni], acc[mi][ni], 0, 0, 0);
        }
      }
    }

    // exchange gates through LDS, then elementwise update
    __syncthreads();
    #pragma unroll
    for (int mi = 0; mi < 2; ++mi)
      #pragma unroll
      for (int ni = 0; ni < 4; ++ni)
        #pragma unroll
        for (int r = 0; r < 4; ++r)
          sh.gs[wave][mi * 16 + quad * 4 + r][ni * 16 + l16] = acc[mi][ni][r];
    __syncthreads();

    #pragma unroll
    for (int q = 0; q < 8; ++q) {
      int e = tid + q * 256;
      int bl = e >> 6, jl = e & 63;
      int b = mb * 32 + bl, j = jb * 64 + jl;
      const float* gb = gbase + (size_t)b * (4 * H_) + j;
      float gi = sh.gs[0][bl][jl] + gb[0];
      float gf = sh.gs[1][bl][jl] + gb[H_];
      float gg = sh.gs[2][bl][jl] + gb[2 * H_];
      float go = sh.gs[3][bl][jl] + gb[3 * H_];
      size_t sidx = (size_t)b * H_ + j;
      float m = mS[sidx];
      m = sigm(gf) * m + sigm(gi) * tanhf(gg);
      float h = sigm(go) * tanhf(m);
      mS[sidx] = m;
      hnext[sidx] = f2bf(h);
    }
  } else if (p >= 1 && bid >= GJOBS && bid < GJOBS + FJOBS) {
    // ---------------- fc(p-1) ----------------
    const int t   = p - 1;
    const int fid = bid - GJOBS;
    const int m0 = (fid / 19) * 64;
    const int n0 = (fid % 19) * 64;
    const int wm = wave & 1, wn = wave >> 1;
    f32x4 acc[2][2] = {};

    for (int kb = 0; kb < H_; kb += 64) {
      __syncthreads();
      #pragma unroll
      for (int pp = 0; pp < 2; ++pp) {
        int r = ar + pp * 32;
        *(uint4*)&sh.f.A[r][ac] = *(const uint4*)&hcur[(size_t)(m0 + r) * H_ + kb + ac];
        *(uint4*)&sh.f.B[r][ac] = *(const uint4*)&WfcB[(size_t)(n0 + r) * H_ + kb + ac];
      }
      __syncthreads();
      #pragma unroll
      for (int ks = 0; ks < 64; ks += 32) {
        s16x8 a0v = *(const s16x8*)&sh.f.A[wm * 32      + l16][ks + quad * 8];
        s16x8 a1v = *(const s16x8*)&sh.f.A[wm * 32 + 16 + l16][ks + quad * 8];
        s16x8 b0v = *(const s16x8*)&sh.f.B[wn * 32      + l16][ks + quad * 8];
        s16x8 b1v = *(const s16x8*)&sh.f.B[wn * 32 + 16 + l16][ks + quad * 8];
        acc[0][0] = __builtin_amdgcn_mfma_f32_16x16x32_bf16(a0v, b0v, acc[0][0], 0, 0, 0);
        acc[0][1] = __builtin_amdgcn_mfma_f32_16x16x32_bf16(a0v, b1v, acc[0][1], 0, 0, 0);
        acc[1][0] = __builtin_amdgcn_mfma_f32_16x16x32_bf16(a1v, b0v, acc[1][0], 0, 0, 0);
        acc[1][1] = __builtin_amdgcn_mfma_f32_16x16x32_bf16(a1v, b1v, acc[1][1], 0, 0, 0);
      }
    }

    #pragma unroll
    for (int mi = 0; mi < 2; ++mi) {
      #pragma unroll
      for (int ni = 0; ni < 2; ++ni) {
        #pragma unroll
        for (int r = 0; r < 4; ++r) {
          int m = m0 + wm * 32 + mi * 16 + quad * 4 + r;
          int n = n0 + wn * 32 + ni * 16 + l16;
          if (n < FCOUT) {
            float rv = fmaxf(acc[mi][ni][r] + b_fc[n], 0.f);
            float msk = (t < length[m]) ? 1.f : 0.f;
            if (n < L_) {
              out[(size_t)m * (T_ * L_) + t * L_ + n] = rv * msk;
            } else if (n < L_ + H_) {
              out[(size_t)(B_ * T_ * L_) + (size_t)m * (T_ * H_) + t * H_ + (n - L_)] = rv * msk;
            } else if (n == L_ + H_) {
              out[(size_t)B_ * T_ * (L_ + H_) + m * T_ + t] = expf(rv) * msk;
            } else {
              out[(size_t)B_ * T_ * (L_ + H_ + 1) + m * T_ + t] = sigm(rv) * msk;
            }
          }
        }
      }
    }
  }
}

// ---------------------------------------------------------------------------
extern "C" void kernel_launch(void* const* d_in, const int* in_sizes, int n_in,
                              void* d_out, int out_size, void* d_ws, size_t ws_size,
                              hipStream_t stream) {
  const float* image  = (const float*)d_in[0];
  const float* label  = (const float*)d_in[1];
  const int*   length = (const int*)  d_in[2];
  const float* W_h    = (const float*)d_in[3];
  const float* b_h    = (const float*)d_in[4];
  const float* W_m    = (const float*)d_in[5];
  const float* b_m    = (const float*)d_in[6];
  const float* W_ih   = (const float*)d_in[7];
  const float* W_hh   = (const float*)d_in[8];
  const float* b_ih   = (const float*)d_in[9];
  const float* b_hh   = (const float*)d_in[10];
  const float* W_fc   = (const float*)d_in[11];
  const float* b_fc   = (const float*)d_in[12];
  float* out = (float*)d_out;

  char* ws = (char*)d_ws;
  size_t off = 0;
  auto alloc = [&](size_t bytes) -> void* {
    void* p = ws + off;
    off = (off + bytes + 255) & ~(size_t)255;
    return p;
  };
  u16*   meanB = (u16*)  alloc((size_t)B_ * E_ * 2);
  u16*   WhB   = (u16*)  alloc((size_t)H_ * E_ * 2);
  u16*   WmB   = (u16*)  alloc((size_t)H_ * E_ * 2);
  u16*   WihE  = (u16*)  alloc((size_t)4 * H_ * E_ * 2);
  u16*   WihL  = (u16*)  alloc((size_t)4 * H_ * L_ * 2);
  u16*   WhhB  = (u16*)  alloc((size_t)4 * H_ * H_ * 2);
  u16*   WfcB  = (u16*)  alloc((size_t)FCPAD * H_ * 2);
  u16*   labB  = (u16*)  alloc((size_t)B_ * T_ * L_ * 2);
  float* gbase = (float*)alloc((size_t)B_ * 4 * H_ * 4);
  u16*   hbuf0 = (u16*)  alloc((size_t)B_ * H_ * 2);
  u16*   hbuf1 = (u16*)  alloc((size_t)B_ * H_ * 2);
  float* mS    = (float*)alloc((size_t)B_ * H_ * 4);

  auto cvt = [&](const float* in, u16* o, int rows, int src_rows, int in_ld,
                 int in_off, int cols) {
    long total = (long)rows * cols;
    int blocks = (int)((total + 255) / 256);
    cvt_bf16<<<blocks, 256, 0, stream>>>(in, o, src_rows, in_ld, in_off, cols, total);
  };

  // --- setup: weight/label conversion to bf16 ---
  cvt(W_h,  WhB,  H_,     H_,     E_,      0,  E_);
  cvt(W_m,  WmB,  H_,     H_,     E_,      0,  E_);
  cvt(W_ih, WihE, 4 * H_, 4 * H_, E_ + L_, 0,  E_);   // columns [0, E)
  cvt(W_ih, WihL, 4 * H_, 4 * H_, E_ + L_, E_, L_);   // columns [E, E+L)
  cvt(W_hh, WhhB, 4 * H_, 4 * H_, H_,      0,  H_);
  cvt(W_fc, WfcB, FCPAD,  FCOUT,  H_,      0,  H_);   // zero-padded rows
  cvt(label, labB, B_, B_, T_ * L_, 0, T_ * L_);

  img_mean_k<<<(B_ * E_) / 256, 256, 0, stream>>>(image, meanB);

  // --- setup GEMMs ---
  // h0 = tanh(mean @ W_h^T + b_h) -> bf16 (h_state[-1] in hbuf0)
  gemm_nt<1><<<dim3(B_ / 64, H_ / 64), 256, 0, stream>>>(
      meanB, E_, WhB, E_, E_, b_h, nullptr, nullptr, hbuf0, H_);
  // m0 = tanh(mean @ W_m^T + b_m) -> f32
  gemm_nt<2><<<dim3(B_ / 64, H_ / 64), 256, 0, stream>>>(
      meanB, E_, WmB, E_, E_, b_m, nullptr, mS, nullptr, H_);
  // gates_base = mean @ W_ihE^T + b_ih + b_hh -> f32
  gemm_nt<0><<<dim3(B_ / 64, (4 * H_) / 64), 256, 0, stream>>>(
      meanB, E_, WihE, E_, E_, b_ih, b_hh, gbase, nullptr, 4 * H_);

  // --- the scan: one launch per phase; kernel boundary = sync ---
  for (int p = 0; p <= T_; ++p) {
    u16* hcur  = (p & 1) ? hbuf1 : hbuf0;
    u16* hnext = (p & 1) ? hbuf0 : hbuf1;
    step_k<<<GJOBS + FJOBS, 256, 0, stream>>>(
        labB, WihL, WhhB, WfcB, gbase, b_fc, hcur, hnext, mS, length, out, p);
  }
}